// Round 3
// baseline (372.589 us; speedup 1.0000x reference)
//
#include <hip/hip_runtime.h>

#define IMG_H 128
#define IMG_W 128
#define OUT_H 127   // valid conv output rows
#define OUT_W 127   // valid conv output cols

// ---------------------------------------------------------------------------
// Kernel 1: per image, sum over the 127x127 map of sigmoid(conv2x2 + bias).
// One block per image, 256 threads = 4 waves; wave w owns rows [32w, 32w+32).
// Per output row, a lane loads 4 floats of the bottom input row and rotates
// them into the "top" registers for the next row -> each input row fetched
// from HBM once.  Lane l produces output cols l and 64+l.
// ---------------------------------------------------------------------------
__global__ __launch_bounds__(256) void conv_sig_sum_kernel(
    const float* __restrict__ data,
    const float* __restrict__ conv_w,
    const float* __restrict__ conv_b,
    float* __restrict__ img_sum)
{
    const int b    = blockIdx.x;
    const float* img = data + (size_t)b * (IMG_H * IMG_W);
    const int tid  = threadIdx.x;
    const int wid  = tid >> 6;
    const int lane = tid & 63;

    const float w00 = conv_w[0], w01 = conv_w[1];
    const float w10 = conv_w[2], w11 = conv_w[3];
    const float bias = conv_b[0];

    const int r0 = wid * 32;
    const int r1 = min(r0 + 32, OUT_H);   // exclusive; wave 3 gets 31 rows

    float acc = 0.f;

    // top-row registers for input row r0
    const float* rt = img + r0 * IMG_W;
    float t0  = rt[lane];                                  // col lane
    float t0n = rt[lane + 1];                              // col lane+1 (<=64, in-bounds)
    float t1  = rt[64 + lane];                             // col 64+lane
    float t1n = (lane < 63) ? rt[65 + lane] : 0.f;         // col 65+lane (<=127)

    for (int r = r0; r < r1; ++r) {
        const float* rb = img + (r + 1) * IMG_W;           // bottom input row
        float b0  = rb[lane];
        float b0n = rb[lane + 1];                          // lane63 -> col 64, valid
        float b1  = rb[64 + lane];
        float b1n = (lane < 63) ? rb[65 + lane] : 0.f;     // guard col 128 (OOB at last img)

        // output col = lane  (0..63, always valid since 63 < 127)
        {
            float v = w00 * t0 + w01 * t0n + w10 * b0 + w11 * b0n + bias;
            float e = __expf(-v);
            acc += __builtin_amdgcn_rcpf(1.0f + e);
        }
        // output col = 64+lane (valid while 64+lane <= 126)
        if (lane < 63) {
            float v = w00 * t1 + w01 * t1n + w10 * b1 + w11 * b1n + bias;
            float e = __expf(-v);
            acc += __builtin_amdgcn_rcpf(1.0f + e);
        }

        t0 = b0; t0n = b0n; t1 = b1; t1n = b1n;
    }

    // wave reduction (64 lanes), then cross-wave via LDS
    #pragma unroll
    for (int off = 32; off > 0; off >>= 1)
        acc += __shfl_down(acc, off, 64);

    __shared__ float wsum[4];
    if (lane == 0) wsum[wid] = acc;
    __syncthreads();
    if (tid == 0)
        img_sum[b] = wsum[0] + wsum[1] + wsum[2] + wsum[3];
}

// ---------------------------------------------------------------------------
// Kernel 2: tiny head.  [4096] sums -> means -> [2048,2] -> 4 tanh-affine
// layers -> final linear -> sum of squares -> exp(-gamma * s).
// Single block, 256 threads, 8 rows per thread.
// ---------------------------------------------------------------------------
__global__ __launch_bounds__(256) void fraud_head_kernel(
    const float* __restrict__ img_sum,
    const float* __restrict__ fraud_W,   // [4,2,2]
    const float* __restrict__ fraud_b,   // [4,2]
    const float* __restrict__ scale,     // [4,2]
    const float* __restrict__ shift,     // [4,2]
    const float* __restrict__ final_W,   // [1,2]
    const float* __restrict__ final_b,   // [1]
    float* __restrict__ out)
{
    const int tid = threadIdx.x;
    const float inv_npix = 1.0f / (float)(OUT_H * OUT_W);

    float ssq = 0.f;
    for (int r = tid; r < 2048; r += 256) {
        float x0 = img_sum[2 * r + 0] * inv_npix;
        float x1 = img_sum[2 * r + 1] * inv_npix;
        #pragma unroll
        for (int l = 0; l < 4; ++l) {
            float a00 = fraud_W[l * 4 + 0], a01 = fraud_W[l * 4 + 1];
            float a10 = fraud_W[l * 4 + 2], a11 = fraud_W[l * 4 + 3];
            float y0 = tanhf(x0 * a00 + x1 * a01 + fraud_b[l * 2 + 0])
                           * scale[l * 2 + 0] + shift[l * 2 + 0];
            float y1 = tanhf(x0 * a10 + x1 * a11 + fraud_b[l * 2 + 1])
                           * scale[l * 2 + 1] + shift[l * 2 + 1];
            x0 = y0; x1 = y1;
        }
        float o = x0 * final_W[0] + x1 * final_W[1] + final_b[0];
        ssq += o * o;
    }

    #pragma unroll
    for (int off = 32; off > 0; off >>= 1)
        ssq += __shfl_down(ssq, off, 64);

    __shared__ float wsum[4];
    const int wid = tid >> 6, lane = tid & 63;
    if (lane == 0) wsum[wid] = ssq;
    __syncthreads();
    if (tid == 0) {
        float total = wsum[0] + wsum[1] + wsum[2] + wsum[3];
        out[0] = __expf(-1e-4f * total);
    }
}

// ---------------------------------------------------------------------------
extern "C" void kernel_launch(void* const* d_in, const int* in_sizes, int n_in,
                              void* d_out, int out_size, void* d_ws, size_t ws_size,
                              hipStream_t stream) {
    const float* data    = (const float*)d_in[0];
    const float* conv_w  = (const float*)d_in[1];
    const float* conv_b  = (const float*)d_in[2];
    const float* fraud_W = (const float*)d_in[3];
    const float* fraud_b = (const float*)d_in[4];
    const float* scale   = (const float*)d_in[5];
    const float* shift   = (const float*)d_in[6];
    const float* final_W = (const float*)d_in[7];
    const float* final_b = (const float*)d_in[8];
    float* out     = (float*)d_out;
    float* img_sum = (float*)d_ws;       // 4096 floats, fully rewritten each call

    conv_sig_sum_kernel<<<4096, 256, 0, stream>>>(data, conv_w, conv_b, img_sum);
    fraud_head_kernel<<<1, 256, 0, stream>>>(img_sum, fraud_W, fraud_b,
                                             scale, shift, final_W, final_b, out);
}